// Round 4
// baseline (202.676 us; speedup 1.0000x reference)
//
#include <hip/hip_runtime.h>
#include <cstdint>

// Two-link planar arm forward dynamics: qdd = M(q)^-1 (tau - h(q,dq)).
// fp32 in / fp32 out. Purely elementwise -> memory/latency-bound.
//
// Round-8 post-mortem: sc0 sc1 nt stores FAILED correctness (absmax ~= max
// |ref|): harness memsets output through the caches, system-scope stores
// wrote to HBM without invalidating the cached zero lines -> verification
// read stale zeros. Lesson: output lines occupy L3 regardless (poison
// memset allocates them); no-allocate stores are structurally unusable.
//
// Round-9 (last lever): FETCH pinned at 98/192 MB because nt LOADS mark
// inputs evict-first in L2/L3 while output/poison lines are temporal ->
// replacement preferentially evicts what we re-read. Hybrid: q (64 MB)
// via plain temporal loads (demand ~2.5 B/cyc/CU, under the ~3.6 B/cyc
// all-plain L1-throttle point, so no round-4 regression), dq/tau stay nt.
// Temporal q should converge to L3-resident across dispatches.
// Predict: FETCH 98 -> 65-80 MB, dur 50.7 -> 46-48 us, WRITE unchanged.
// Pre-commit: if dur >= 50 us or FETCH unchanged -> declare ROOFLINE.

#define BLOCK 256
#define GRID  2048   // 8 blocks/CU * 256 CU (best measured config)

typedef float f4 __attribute__((ext_vector_type(4)));

__device__ __forceinline__ f4 fd_compute(f4 qv, f4 dv, f4 tv) {
    // Arm constants (L1=L2=1, C1=C2=0.5, M1=M2=1, I1=I2=0.1, G=9.81)
    const float alpha = 1.7f;     // I1 + M1*C1^2 + I2 + M2*(L1^2 + C2^2)
    const float beta  = 0.5f;     // M2*L1*C2
    const float delta = 0.35f;    // I2 + M2*C2^2  (== M22)
    const float G     = 9.81f;
    const float gA    = 1.5f * G; // (M1*C1 + M2*L1)*G
    const float gB    = 0.5f * G; // M2*C2*G

    f4 ov;

#pragma unroll
    for (int j = 0; j < 2; ++j) {
        float q1   = qv[2 * j + 0];
        float q2   = qv[2 * j + 1];
        float dq1  = dv[2 * j + 0];
        float dq2  = dv[2 * j + 1];
        float tau1 = tv[2 * j + 0];
        float tau2 = tv[2 * j + 1];

        float c2 = __cosf(q2);
        float s2 = __sinf(q2);

        float M11 = alpha + 2.0f * beta * c2;
        float M12 = delta + beta * c2;
        float M22 = delta;

        float cq1  = __cosf(q1);
        float cq12 = __cosf(q1 + q2);

        float g1 = gA * cq1 + gB * cq12;
        float g2 = gB * cq12;

        float h1 = -beta * s2 * (2.0f * dq1 * dq2 + dq2 * dq2) + g1;
        float h2 =  beta * s2 * dq1 * dq1 + g2;

        float r1 = tau1 - h1;
        float r2 = tau2 - h2;

        float det  = M11 * M22 - M12 * M12;
        float rdet = __builtin_amdgcn_rcpf(det);   // v_rcp_f32, ~1 ulp

        ov[2 * j + 0] = (M22 * r1 - M12 * r2) * rdet;
        ov[2 * j + 1] = (M11 * r2 - M12 * r1) * rdet;
    }
    return ov;
}

__global__ __launch_bounds__(BLOCK) void fd_qdd_kernel(
    const f4* __restrict__ qp,
    const f4* __restrict__ dqp,
    const f4* __restrict__ taup,
    f4* __restrict__ outp,
    int nvec)  // number of float4 groups (= 2 rows each)
{
    const int tid = blockIdx.x * BLOCK + threadIdx.x;
    const int nt  = GRID * BLOCK;          // total threads (grid-stride)
    const int nt2 = 2 * nt;

    // Main loop: 2 elements pipelined — all 6 loads issued before either
    // compute. q: plain temporal loads (L3-pin); dq/tau: nt streaming.
    int idx = tid;
    for (; idx + nt < nvec; idx += nt2) {
        int i0 = idx, i1 = idx + nt;
        f4 q0 = qp[i0];                                   // temporal
        f4 d0 = __builtin_nontemporal_load(&dqp[i0]);
        f4 t0 = __builtin_nontemporal_load(&taup[i0]);
        f4 q1 = qp[i1];                                   // temporal
        f4 d1 = __builtin_nontemporal_load(&dqp[i1]);
        f4 t1 = __builtin_nontemporal_load(&taup[i1]);

        f4 o0 = fd_compute(q0, d0, t0);
        f4 o1 = fd_compute(q1, d1, t1);

        __builtin_nontemporal_store(o0, &outp[i0]);
        __builtin_nontemporal_store(o1, &outp[i1]);
    }
    // Tail: general-nvec correctness (steps by nt so the i1 half of a
    // partial pipelined pair is also covered).
    for (; idx < nvec; idx += nt) {
        f4 q = qp[idx];
        f4 d = __builtin_nontemporal_load(&dqp[idx]);
        f4 t = __builtin_nontemporal_load(&taup[idx]);
        f4 o = fd_compute(q, d, t);
        __builtin_nontemporal_store(o, &outp[idx]);
    }
}

extern "C" void kernel_launch(void* const* d_in, const int* in_sizes, int n_in,
                              void* d_out, int out_size, void* d_ws, size_t ws_size,
                              hipStream_t stream) {
    const f4* q   = (const f4*)d_in[0];
    const f4* dq  = (const f4*)d_in[1];
    const f4* tau = (const f4*)d_in[2];
    f4*       out = (f4*)d_out;

    int n_elems = in_sizes[0];      // B*2 fp32 elements
    int nvec    = n_elems / 4;      // 4 fp32 per float4 (2 rows)

    fd_qdd_kernel<<<GRID, BLOCK, 0, stream>>>(q, dq, tau, out, nvec);
}

// Round 5
// 200.464 us; speedup vs baseline: 1.0110x; 1.0110x over previous
//
#include <hip/hip_runtime.h>
#include <cstdint>

// Two-link planar arm forward dynamics: qdd = M(q)^-1 (tau - h(q,dq)).
// fp32 in / fp32 out. Purely elementwise -> memory/latency-bound.
//
// FINAL KERNEL — session-best configuration (round 5), restored after the
// lever-space was exhausted:
//   - all-nt loads:   only load flavor that avoids the per-CU L1
//                     miss-tracking throttle (plain=87us, sc0=87us,
//                     hybrid 1-temporal-stream=61us, all-nt=50.7us).
//   - nt stores:      required for correctness to stay cache-coherent
//                     (sc0 sc1 system-scope stores broke verification
//                     against the cached poison memset).
//   - GRID 2048:      1 block-wave; 4x oversubscription raised measured
//                     occupancy 51->67% but cost +6% time.
//   - 2-deep pipeline: 6 outstanding 16B loads/thread; deeper = null
//                     (limiter is per-CU miss cap, not per-wave MLP).
//
// Ceiling statement: 256 MB CU-visible in ~50.7 us = 5.05 TB/s = 80% of
// the 6.29 TB/s pure-copy ceiling, on a 3R+1W stream whose reads are a
// pinned ~50/50 mix of L3 hits (~400cy) and HBM misses (~900cy); FETCH
// is invariant at 98.3/192 MB across every hint/grid/occupancy variant
// => replacement policy + harness traffic set it, not the kernel.
// Throughput = per-CU outstanding-miss cap x avg latency: roofline.

#define BLOCK 256
#define GRID  2048   // 8 blocks/CU * 256 CU

typedef float f4 __attribute__((ext_vector_type(4)));

__device__ __forceinline__ f4 fd_compute(f4 qv, f4 dv, f4 tv) {
    // Arm constants (L1=L2=1, C1=C2=0.5, M1=M2=1, I1=I2=0.1, G=9.81)
    const float alpha = 1.7f;     // I1 + M1*C1^2 + I2 + M2*(L1^2 + C2^2)
    const float beta  = 0.5f;     // M2*L1*C2
    const float delta = 0.35f;    // I2 + M2*C2^2  (== M22)
    const float G     = 9.81f;
    const float gA    = 1.5f * G; // (M1*C1 + M2*L1)*G
    const float gB    = 0.5f * G; // M2*C2*G

    f4 ov;

#pragma unroll
    for (int j = 0; j < 2; ++j) {
        float q1   = qv[2 * j + 0];
        float q2   = qv[2 * j + 1];
        float dq1  = dv[2 * j + 0];
        float dq2  = dv[2 * j + 1];
        float tau1 = tv[2 * j + 0];
        float tau2 = tv[2 * j + 1];

        float c2 = __cosf(q2);
        float s2 = __sinf(q2);

        float M11 = alpha + 2.0f * beta * c2;
        float M12 = delta + beta * c2;
        float M22 = delta;

        float cq1  = __cosf(q1);
        float cq12 = __cosf(q1 + q2);

        float g1 = gA * cq1 + gB * cq12;
        float g2 = gB * cq12;

        float h1 = -beta * s2 * (2.0f * dq1 * dq2 + dq2 * dq2) + g1;
        float h2 =  beta * s2 * dq1 * dq1 + g2;

        float r1 = tau1 - h1;
        float r2 = tau2 - h2;

        float det  = M11 * M22 - M12 * M12;
        float rdet = __builtin_amdgcn_rcpf(det);   // v_rcp_f32, ~1 ulp

        ov[2 * j + 0] = (M22 * r1 - M12 * r2) * rdet;
        ov[2 * j + 1] = (M11 * r2 - M12 * r1) * rdet;
    }
    return ov;
}

__global__ __launch_bounds__(BLOCK) void fd_qdd_kernel(
    const f4* __restrict__ qp,
    const f4* __restrict__ dqp,
    const f4* __restrict__ taup,
    f4* __restrict__ outp,
    int nvec)  // number of float4 groups (= 2 rows each)
{
    const int tid = blockIdx.x * BLOCK + threadIdx.x;
    const int nt  = GRID * BLOCK;          // total threads (grid-stride)
    const int nt2 = 2 * nt;

    // Main loop: 2 elements pipelined — all 6 nt loads issued before
    // either compute (compiler inserts fine-grained vmcnt waits).
    int idx = tid;
    for (; idx + nt < nvec; idx += nt2) {
        int i0 = idx, i1 = idx + nt;
        f4 q0 = __builtin_nontemporal_load(&qp[i0]);
        f4 d0 = __builtin_nontemporal_load(&dqp[i0]);
        f4 t0 = __builtin_nontemporal_load(&taup[i0]);
        f4 q1 = __builtin_nontemporal_load(&qp[i1]);
        f4 d1 = __builtin_nontemporal_load(&dqp[i1]);
        f4 t1 = __builtin_nontemporal_load(&taup[i1]);

        f4 o0 = fd_compute(q0, d0, t0);
        f4 o1 = fd_compute(q1, d1, t1);

        __builtin_nontemporal_store(o0, &outp[i0]);
        __builtin_nontemporal_store(o1, &outp[i1]);
    }
    // Tail: general-nvec correctness (steps by nt so the i1 half of a
    // partial pipelined pair is also covered).
    for (; idx < nvec; idx += nt) {
        f4 q = __builtin_nontemporal_load(&qp[idx]);
        f4 d = __builtin_nontemporal_load(&dqp[idx]);
        f4 t = __builtin_nontemporal_load(&taup[idx]);
        f4 o = fd_compute(q, d, t);
        __builtin_nontemporal_store(o, &outp[idx]);
    }
}

extern "C" void kernel_launch(void* const* d_in, const int* in_sizes, int n_in,
                              void* d_out, int out_size, void* d_ws, size_t ws_size,
                              hipStream_t stream) {
    const f4* q   = (const f4*)d_in[0];
    const f4* dq  = (const f4*)d_in[1];
    const f4* tau = (const f4*)d_in[2];
    f4*       out = (f4*)d_out;

    int n_elems = in_sizes[0];      // B*2 fp32 elements
    int nvec    = n_elems / 4;      // 4 fp32 per float4 (2 rows)

    fd_qdd_kernel<<<GRID, BLOCK, 0, stream>>>(q, dq, tau, out, nvec);
}